// Round 4
// baseline (1150.763 us; speedup 1.0000x reference)
//
#include <hip/hip_runtime.h>
#include <cstddef>

// Problem constants (from reference):
#define L_SEQ  2048
#define B_SZ   2
#define E_DIM  1024
#define H_N    16
#define D_HEAD 64
#define R_DIM  256

typedef unsigned short u16;
using bf16x8 = __attribute__((ext_vector_type(8))) short;   // 8 bf16 (4 VGPRs)
using f32x4  = __attribute__((ext_vector_type(4))) float;   // MFMA accumulator

// RNE fp32 -> bf16 (matches v_cvt semantics)
__device__ __forceinline__ u16 bf16rne(float f) {
    unsigned u = __float_as_uint(f);
    return (u16)((u + 0x7FFFu + ((u >> 16) & 1u)) >> 16);
}
__device__ __forceinline__ float b2f(u16 h) {
    return __uint_as_float(((unsigned)h) << 16);
}

// Async global->LDS, 16B per lane: LDS dest = wave-uniform base + lane*16.
// Source is per-lane (pre-swizzled). Guide §5 / m97 / m173.
__device__ __forceinline__ void gload16(const u16* g, u16* l) {
    __builtin_amdgcn_global_load_lds(
        (const __attribute__((address_space(1))) void*)g,
        (__attribute__((address_space(3))) void*)l, 16, 0, 0);
}

// ---------------------------------------------------------------------------
// fp32 -> bf16 hi/lo conversion (grid-stride, float4 vectorized)
// ---------------------------------------------------------------------------
__global__ __launch_bounds__(256)
void convert_hilo(const float* __restrict__ in, u16* __restrict__ hi,
                  u16* __restrict__ lo, int n4)
{
    for (int i = blockIdx.x * 256 + threadIdx.x; i < n4; i += gridDim.x * 256) {
        float4 v = ((const float4*)in)[i];
        u16 h0 = bf16rne(v.x), h1 = bf16rne(v.y), h2 = bf16rne(v.z), h3 = bf16rne(v.w);
        uint2 hp;
        hp.x = (unsigned)h0 | ((unsigned)h1 << 16);
        hp.y = (unsigned)h2 | ((unsigned)h3 << 16);
        ((uint2*)hi)[i] = hp;
        u16 l0 = bf16rne(v.x - b2f(h0)), l1 = bf16rne(v.y - b2f(h1));
        u16 l2 = bf16rne(v.z - b2f(h2)), l3 = bf16rne(v.w - b2f(h3));
        uint2 lp;
        lp.x = (unsigned)l0 | ((unsigned)l1 << 16);
        lp.y = (unsigned)l2 | ((unsigned)l3 << 16);
        ((uint2*)lo)[i] = lp;
    }
}

// ---------------------------------------------------------------------------
// fp32 [rows][cols] -> bf16 hi/lo transposed [cols][rows]
// ---------------------------------------------------------------------------
__global__ __launch_bounds__(256)
void transpose_f32_hilo(const float* __restrict__ in, u16* __restrict__ oh,
                        u16* __restrict__ ol, int rows, int cols)
{
    __shared__ float t[32][33];
    const int tx = threadIdx.x & 31, ty = threadIdx.x >> 5;
    const int r0 = blockIdx.y * 32, c0 = blockIdx.x * 32;
    #pragma unroll
    for (int i = 0; i < 4; i++)
        t[ty + i * 8][tx] = in[(size_t)(r0 + ty + i * 8) * cols + c0 + tx];
    __syncthreads();
    #pragma unroll
    for (int i = 0; i < 4; i++) {
        float v = t[tx][ty + i * 8];
        u16 h = bf16rne(v);
        size_t o = (size_t)(c0 + ty + i * 8) * rows + r0 + tx;
        oh[o] = h;
        ol[o] = bf16rne(v - b2f(h));
    }
}

// ---------------------------------------------------------------------------
// V [L,B,E] bf16 -> Vt [B*H, D, L] bf16 (per-head transpose so PV is TRANSB)
// ---------------------------------------------------------------------------
__global__ __launch_bounds__(256)
void transpose_v_bf16(const u16* __restrict__ vh, u16* __restrict__ vt)
{
    __shared__ u16 t[32][34];
    const int tx = threadIdx.x & 31, ty = threadIdx.x >> 5;
    const int l0 = blockIdx.x * 32, d0 = blockIdx.y * 32;
    const int z = blockIdx.z, b = z >> 4, h = z & 15;
    #pragma unroll
    for (int i = 0; i < 4; i++)
        t[ty + i * 8][tx] =
            vh[(size_t)((l0 + ty + i * 8) * B_SZ + b) * E_DIM + h * D_HEAD + d0 + tx];
    __syncthreads();
    #pragma unroll
    for (int i = 0; i < 4; i++)
        vt[(size_t)(z * D_HEAD + d0 + ty + i * 8) * L_SEQ + l0 + tx] = t[tx][ty + i * 8];
}

// ---------------------------------------------------------------------------
// mask zero-detection: fast path flag for attn_fused
// ---------------------------------------------------------------------------
__global__ void flag_init(int* f) { if (threadIdx.x == 0) *f = 0; }

__global__ __launch_bounds__(256)
void mask_scan(const float* __restrict__ m, int* __restrict__ f, int n4)
{
    int nz = 0;
    for (int i = blockIdx.x * 256 + threadIdx.x; i < n4; i += gridDim.x * 256) {
        float4 v = ((const float4*)m)[i];
        nz |= (v.x != 0.0f) | (v.y != 0.0f) | (v.z != 0.0f) | (v.w != 0.0f);
    }
    if (nz) atomicOr(f, 1);
}

// ---------------------------------------------------------------------------
// Bias fold: beff = 0.6*b + 0.4*U@(U^T@b)   (tiny, fp32)
// ---------------------------------------------------------------------------
__global__ __launch_bounds__(256)
void bias_fold1(const float* __restrict__ b, const float* __restrict__ U,
                float* __restrict__ tmp)   // tmp[r] = sum_e U[e][r]*b[e]
{
    const int r = threadIdx.x;             // one block of 256
    float s = 0.0f;
    for (int e = 0; e < E_DIM; e++) s += U[(size_t)e * R_DIM + r] * b[e];
    tmp[r] = s;
}

__global__ __launch_bounds__(256)
void bias_fold2(const float* __restrict__ b, const float* __restrict__ U,
                const float* __restrict__ tmp, float* __restrict__ beff)
{
    const int e = blockIdx.x * 256 + threadIdx.x;   // grid 4
    float s = 0.0f;
    for (int r = 0; r < R_DIM; r++) s += U[(size_t)e * R_DIM + r] * tmp[r];
    beff[e] = 0.6f * b[e] + 0.4f * s;
}

// ---------------------------------------------------------------------------
// MFMA GEMM (single batch): C = alpha * A @ B^T + beta * Cin + bias
//   A,B bf16 hi(/lo split); outputs: Cf fp32 and/or Ch/Cl bf16 hi/lo.
//   Staging via global_load_lds w=16: LDS layout [row][granule] with granule
//   position p holding source granule p ^ (row&7) (T2-style swizzle). Since
//   each wave-call covers exactly 8 rows (row&7 == lane>>3), the inverse
//   swizzle is the per-lane constant ((lane&7)^(lane>>3))*16B on the SOURCE
//   address (m173 pattern); compute-side reads unchanged from the verified
//   round-1/3 kernel.
// ---------------------------------------------------------------------------
template <bool SPLIT>
__global__ __launch_bounds__(256)
void gemm_mfma(const u16* __restrict__ Ah, const u16* __restrict__ Al,
               const u16* __restrict__ Bh, const u16* __restrict__ Bl,
               float* __restrict__ Cf, u16* __restrict__ Ch, u16* __restrict__ Cl,
               const u16* __restrict__ Cinh, const u16* __restrict__ Cinl,
               const float* __restrict__ bias,
               int M, int N, int K, int lda, int ldb, int ldc,
               float alpha, float beta)
{
    constexpr int BM = 128, BN = 128, BK = 64;
    constexpr int ALO = BM * BK, BLO = BN * BK;
    __shared__ __align__(16) u16 As[(SPLIT ? 2 : 1) * BM * BK];
    __shared__ __align__(16) u16 Bs[(SPLIT ? 2 : 1) * BN * BK];

    const int tid = threadIdx.x;
    const int tm = blockIdx.y * BM, tn = blockIdx.x * BN;
    const int lane = tid & 63;
    const int fr = lane & 15, kg = lane >> 4;
    const int wave = tid >> 6;
    const int wm = (wave >> 1) * 64, wn = (wave & 1) * 64;

    const int sR8 = lane >> 3;                  // row within 8-row group
    const int sG  = ((lane & 7) ^ sR8) * 8;     // pre-swizzled source granule (u16)

    f32x4 acc[4][4] = {};

    for (int k0 = 0; k0 < K; k0 += BK) {
        #pragma unroll
        for (int c = 0; c < 4; c++) {
            const int r0 = (c * 4 + wave) * 8;  // wave-uniform
            gload16(Ah + (size_t)(tm + r0 + sR8) * lda + k0 + sG, &As[r0 * BK]);
            gload16(Bh + (size_t)(tn + r0 + sR8) * ldb + k0 + sG, &Bs[r0 * BK]);
            if constexpr (SPLIT) {
                gload16(Al + (size_t)(tm + r0 + sR8) * lda + k0 + sG, &As[ALO + r0 * BK]);
                gload16(Bl + (size_t)(tn + r0 + sR8) * ldb + k0 + sG, &Bs[BLO + r0 * BK]);
            }
        }
        __syncthreads();   // drains vmcnt (compiler emits full waitcnt before barrier)

        #pragma unroll
        for (int ks = 0; ks < 2; ks++) {
            bf16x8 ah[4], al[4];
            #pragma unroll
            for (int m = 0; m < 4; m++) {
                int row = wm + m * 16 + fr;
                int p = (ks * 4 + kg) ^ (row & 7);
                ah[m] = *(const bf16x8*)&As[row * BK + p * 8];
                if constexpr (SPLIT)
                    al[m] = *(const bf16x8*)&As[ALO + row * BK + p * 8];
            }
            #pragma unroll
            for (int n = 0; n < 4; n++) {
                int col = wn + n * 16 + fr;
                int p = (ks * 4 + kg) ^ (col & 7);
                bf16x8 bh = *(const bf16x8*)&Bs[col * BK + p * 8];
                #pragma unroll
                for (int m = 0; m < 4; m++)
                    acc[m][n] = __builtin_amdgcn_mfma_f32_16x16x32_bf16(ah[m], bh, acc[m][n], 0, 0, 0);
                if constexpr (SPLIT) {
                    bf16x8 bl = *(const bf16x8*)&Bs[BLO + col * BK + p * 8];
                    #pragma unroll
                    for (int m = 0; m < 4; m++) {
                        acc[m][n] = __builtin_amdgcn_mfma_f32_16x16x32_bf16(al[m], bh, acc[m][n], 0, 0, 0);
                        acc[m][n] = __builtin_amdgcn_mfma_f32_16x16x32_bf16(ah[m], bl, acc[m][n], 0, 0, 0);
                    }
                }
            }
        }
        __syncthreads();
    }

    // epilogue: C/D layout col=lane&15, row=(lane>>4)*4+reg (m89-verified)
    #pragma unroll
    for (int m = 0; m < 4; m++) {
        int row0 = tm + wm + m * 16 + kg * 4;
        #pragma unroll
        for (int n = 0; n < 4; n++) {
            int col = tn + wn + n * 16 + fr;
            float bv = bias ? bias[col] : 0.0f;
            #pragma unroll
            for (int j = 0; j < 4; j++) {
                size_t idx = (size_t)(row0 + j) * ldc + col;
                float v = alpha * acc[m][n][j] + bv;
                if (beta != 0.0f) {
                    float ci = b2f(Cinh[idx]);
                    if (Cinl) ci += b2f(Cinl[idx]);
                    v += beta * ci;
                }
                if (Cf) Cf[idx] = v;
                if (Ch) {
                    u16 h = bf16rne(v);
                    Ch[idx] = h;
                    if (Cl) Cl[idx] = bf16rne(v - b2f(h));
                }
            }
        }
    }
}

// ---------------------------------------------------------------------------
// Fused attention (verified round 3; staging moved to global_load_lds):
// scores (QK^T/8 + mask) -> exact 2-pass softmax -> attn weights (fp32) +
// PV context (bf16 hi/lo). 64 q-rows per block, 4 waves x 16 q-rows.
// ---------------------------------------------------------------------------
__global__ __launch_bounds__(256)
void attn_fused(const u16* __restrict__ Qc, const u16* __restrict__ Kc,
                const u16* __restrict__ Vt, float* __restrict__ attn,
                u16* __restrict__ ctxh, u16* __restrict__ ctxl,
                const float* __restrict__ mask, const int* __restrict__ maskFlag)
{
    __shared__ __align__(16) u16 Qs[64 * 64];   // [q][k]  swizzled, 8 KB
    __shared__ __align__(16) u16 Ks[64 * 64];   // [kv][k] swizzled, 8 KB
    __shared__ __align__(16) u16 Vs[64 * 64];   // [d][kv] swizzled, 8 KB
    __shared__ __align__(16) u16 Ps[4][16 * 64];// per-wave [q][kv] swizzled, 8 KB

    const int tid = threadIdx.x;
    const int z  = blockIdx.y;                 // b*16 + h
    const int q0 = blockIdx.x * 64;
    const int qkOff = (z >> 4) * E_DIM + (z & 15) * D_HEAD;
    const long vtOff = (long)z * D_HEAD * L_SEQ;
    const long aOff  = (long)z * L_SEQ * L_SEQ;
    const int ldq = B_SZ * E_DIM;              // 2048

    const int lane = tid & 63;
    const int fr = lane & 15, kg = lane >> 4;
    const int wave = tid >> 6;
    const int wq = wave * 16;

    const bool useMask = maskFlag[0] != 0;
    const int sR8 = lane >> 3;
    const int sG  = ((lane & 7) ^ sR8) * 8;    // pre-swizzled source granule

    // ---- stage Q tile [64][64] via global_load_lds ----
    #pragma unroll
    for (int c = 0; c < 2; c++) {
        const int r0 = (c * 4 + wave) * 8;
        gload16(Qc + (size_t)(q0 + r0 + sR8) * ldq + qkOff + sG, &Qs[r0 * 64]);
    }
    __syncthreads();
    bf16x8 qf[2];
    #pragma unroll
    for (int ks = 0; ks < 2; ks++) {
        int row = wq + fr;
        qf[ks] = *(const bf16x8*)&Qs[row * 64 + ((ks * 4 + kg) ^ (row & 7)) * 8];
    }
    __syncthreads();   // Qs dead

    float mrow[4], lrow[4];
    #pragma unroll
    for (int j = 0; j < 4; j++) { mrow[j] = -3.4e38f; lrow[j] = 0.0f; }

    // ================= pass 1: row max & sum =================
    for (int kt = 0; kt < L_SEQ / 64; kt++) {
        const int kv0 = kt * 64;
        #pragma unroll
        for (int c = 0; c < 2; c++) {
            const int r0 = (c * 4 + wave) * 8;
            gload16(Kc + (size_t)(kv0 + r0 + sR8) * ldq + qkOff + sG, &Ks[r0 * 64]);
        }
        __syncthreads();

        f32x4 acc[4] = {};
        #pragma unroll
        for (int ks = 0; ks < 2; ks++) {
            #pragma unroll
            for (int n = 0; n < 4; n++) {
                int col = n * 16 + fr;
                bf16x8 bh = *(const bf16x8*)&Ks[col * 64 + ((ks * 4 + kg) ^ (col & 7)) * 8];
                acc[n] = __builtin_amdgcn_mfma_f32_16x16x32_bf16(qf[ks], bh, acc[n], 0, 0, 0);
            }
        }
        __syncthreads();   // Ks consumed before restage

        #pragma unroll
        for (int j = 0; j < 4; j++) {
            float v[4];
            #pragma unroll
            for (int n = 0; n < 4; n++) {
                v[n] = acc[n][j] * 0.125f;
                if (useMask)
                    v[n] += mask[(size_t)(q0 + wq + kg * 4 + j) * L_SEQ + kv0 + n * 16 + fr];
            }
            float t0 = fmaxf(fmaxf(v[0], v[1]), fmaxf(v[2], v[3]));
            float nm = fmaxf(mrow[j], t0);
            float sc = __expf(mrow[j] - nm);
            float s  = __expf(v[0] - nm) + __expf(v[1] - nm)
                     + __expf(v[2] - nm) + __expf(v[3] - nm);
            lrow[j] = lrow[j] * sc + s;
            mrow[j] = nm;
        }
    }

    // merge (m,l) across the 16-lane fr-group
    #pragma unroll
    for (int j = 0; j < 4; j++) {
        float m_ = mrow[j], l_ = lrow[j];
        #pragma unroll
        for (int off = 1; off < 16; off <<= 1) {
            float mo = __shfl_xor(m_, off, 64);
            float lo2 = __shfl_xor(l_, off, 64);
            float M = fmaxf(m_, mo);
            l_ = l_ * __expf(m_ - M) + lo2 * __expf(mo - M);
            m_ = M;
        }
        mrow[j] = m_;
        lrow[j] = 1.0f / l_;
    }

    // ================= pass 2: normalized attn write + PV =================
    u16* Pw = &Ps[wave][0];
    f32x4 acc_o[4] = {};

    for (int kt = 0; kt < L_SEQ / 64; kt++) {
        const int kv0 = kt * 64;
        #pragma unroll
        for (int c = 0; c < 2; c++) {
            const int r0 = (c * 4 + wave) * 8;
            gload16(Kc + (size_t)(kv0 + r0 + sR8) * ldq + qkOff + sG, &Ks[r0 * 64]);
            gload16(Vt + vtOff + (size_t)(r0 + sR8) * L_SEQ + kv0 + sG, &Vs[r0 * 64]);
        }
        __syncthreads();

        f32x4 acc[4] = {};
        #pragma unroll
        for (int ks = 0; ks < 2; ks++) {
            #pragma unroll
            for (int n = 0; n < 4; n++) {
                int col = n * 16 + fr;
                bf16x8 bh = *(const bf16x8*)&Ks[col * 64 + ((ks * 4 + kg) ^ (col & 7)) * 8];
                acc[n] = __builtin_amdgcn_mfma_f32_16x16x32_bf16(qf[ks], bh, acc[n], 0, 0, 0);
            }
        }

        // P = exp(s - m) / l : write fp32 attn + bf16 into wave-private LDS
        #pragma unroll
        for (int n = 0; n < 4; n++) {
            #pragma unroll
            for (int j = 0; j < 4; j++) {
                int row = kg * 4 + j;
                int col = n * 16 + fr;
                float v = acc[n][j] * 0.125f;
                if (useMask)
                    v += mask[(size_t)(q0 + wq + row) * L_SEQ + kv0 + col];
                float p = __expf(v - mrow[j]) * lrow[j];
                attn[aOff + (size_t)(q0 + wq + row) * L_SEQ + kv0 + col] = p;
                Pw[row * 64 + ((col >> 3) ^ (row & 7)) * 8 + (col & 7)] = bf16rne(p);
            }
        }

        // pin order: Pw writes precede same-wave Pw reads (rule #18 class)
        asm volatile("" ::: "memory");

        // PV: O[16 q][64 d] += P[16 q][64 kv] @ Vt[64 d][64 kv]^T
        #pragma unroll
        for (int ks = 0; ks < 2; ks++) {
            int rowA = fr;
            bf16x8 pa = *(const bf16x8*)&Pw[rowA * 64 + ((ks * 4 + kg) ^ (rowA & 7)) * 8];
            #pragma unroll
            for (int n = 0; n < 4; n++) {
                int d = n * 16 + fr;
                bf16x8 vb = *(const bf16x8*)&Vs[d * 64 + ((ks * 4 + kg) ^ (d & 7)) * 8];
                acc_o[n] = __builtin_amdgcn_mfma_f32_16x16x32_bf16(pa, vb, acc_o[n], 0, 0, 0);
            }
        }
        __syncthreads();   // Ks/Vs consumed before restage
    }

    // ---- epilogue: ctx bf16 hi/lo, head-sliced [L,B,E] ----
    #pragma unroll
    for (int n = 0; n < 4; n++) {
        #pragma unroll
        for (int j = 0; j < 4; j++) {
            int row = q0 + wq + kg * 4 + j;
            int d = n * 16 + fr;
            float v = acc_o[n][j];
            size_t idx = (size_t)row * ldq + qkOff + d;
            u16 h = bf16rne(v);
            ctxh[idx] = h;
            ctxl[idx] = bf16rne(v - b2f(h));
        }
    }
}

// ---------------------------------------------------------------------------
extern "C" void kernel_launch(void* const* d_in, const int* in_sizes, int n_in,
                              void* d_out, int out_size, void* d_ws, size_t ws_size,
                              hipStream_t stream)
{
    const float* x    = (const float*)d_in[0];
    const float* mask = (const float*)d_in[1];
    const float* Wq   = (const float*)d_in[2];
    const float* bq   = (const float*)d_in[3];
    const float* Wk   = (const float*)d_in[4];
    const float* bk   = (const float*)d_in[5];
    const float* Wv   = (const float*)d_in[6];
    const float* bv   = (const float*)d_in[7];
    const float* Wo   = (const float*)d_in[8];
    const float* bo   = (const float*)d_in[9];
    const float* U    = (const float*)d_in[10];

    float* out   = (float*)d_out;                               // [L,B,E]
    float* attnF = out + (size_t)L_SEQ * B_SZ * E_DIM;          // [B,H,L,L]

    const int SZ  = L_SEQ * B_SZ * E_DIM;   // 4,194,304
    const int WSZ = E_DIM * E_DIM;          // 1,048,576
    const int USZ = E_DIM * R_DIM;          //   262,144

    // ---- persistent ws (survives attn-region overwrite): ~44 MB ----
    u16* Qch  = (u16*)d_ws;
    u16* Kch  = Qch + SZ;
    u16* Vth  = Kch + SZ;          // V^T per head: [B*H, D, L]
    u16* ctxh = Vth + SZ;
    u16* ctxl = ctxh + SZ;
    u16* Woh  = ctxl + SZ;
    u16* Wol  = Woh + WSZ;
    int* maskFlag = (int*)(Wol + WSZ);

    // ---- pre-attn scratch in the (not-yet-written) attn region (~59 MB) ----
    u16* sc   = (u16*)attnF;
    u16* xh   = sc;          u16* xl   = xh + SZ;
    u16* Wqh  = xl + SZ;     u16* Wql  = Wqh + WSZ;
    u16* Wkh  = Wql + WSZ;   u16* Wkl  = Wkh + WSZ;
    u16* Wvh  = Wkl + WSZ;   u16* Wvl  = Wvh + WSZ;
    u16* Uh   = Wvl + WSZ;   u16* Ul   = Uh + USZ;
    u16* Uth  = Ul + USZ;    u16* Utl  = Uth + USZ;   // U^T [R,E]
    u16* WqTh = Utl + USZ;   u16* WqTl = WqTh + WSZ;  // Wq^T [E,E]
    u16* WkTh = WqTl + WSZ;  u16* WkTl = WkTh + WSZ;
    u16* GTqh = WkTl + WSZ;  u16* GTql = GTqh + USZ;  // (Wq^T U) [E,R]
    u16* GTkh = GTql + USZ;  u16* GTkl = GTkh + USZ;
    u16* Wfqh = GTkl + USZ;  u16* Wfql = Wfqh + WSZ;  // folded weights [E,E]
    u16* Wfkh = Wfql + WSZ;  u16* Wfkl = Wfkh + WSZ;
    u16* Vh   = Wfkl + WSZ;                           // V bf16 [L,B,E]
    float* bqe  = (float*)(Vh + SZ);                  // folded biases (fp32)
    float* bke  = bqe + E_DIM;
    float* tmpv = bke + E_DIM;

    const dim3 blk(256);
    const int M = L_SEQ * B_SZ;  // 4096

    // 0a. mask zero-detection flag
    hipLaunchKernelGGL(flag_init, dim3(1), dim3(64), 0, stream, maskFlag);
    hipLaunchKernelGGL(mask_scan, dim3(512), blk, 0, stream,
                       mask, maskFlag, (L_SEQ * L_SEQ) / 4);

    // 0b. fp32 -> bf16 hi/lo conversions + transposes
    hipLaunchKernelGGL(convert_hilo, dim3(2048), blk, 0, stream, x,  xh,  xl,  SZ / 4);
    hipLaunchKernelGGL(convert_hilo, dim3(512),  blk, 0, stream, Wq, Wqh, Wql, WSZ / 4);
    hipLaunchKernelGGL(convert_hilo, dim3(512),  blk, 0, stream, Wk, Wkh, Wkl, WSZ / 4);
    hipLaunchKernelGGL(convert_hilo, dim3(512),  blk, 0, stream, Wv, Wvh, Wvl, WSZ / 4);
    hipLaunchKernelGGL(convert_hilo, dim3(512),  blk, 0, stream, Wo, Woh, Wol, WSZ / 4);
    hipLaunchKernelGGL(convert_hilo, dim3(128),  blk, 0, stream, U,  Uh,  Ul,  USZ / 4);
    hipLaunchKernelGGL(transpose_f32_hilo, dim3(R_DIM / 32, E_DIM / 32), blk, 0, stream,
                       U, Uth, Utl, E_DIM, R_DIM);
    hipLaunchKernelGGL(transpose_f32_hilo, dim3(E_DIM / 32, E_DIM / 32), blk, 0, stream,
                       Wq, WqTh, WqTl, E_DIM, E_DIM);
    hipLaunchKernelGGL(transpose_f32_hilo, dim3(E_DIM / 32, E_DIM / 32), blk, 0, stream,
                       Wk, WkTh, WkTl, E_DIM, E_DIM);

    // 0c. bias folds: beff = 0.6*b + 0.4*U@(U^T@b)
    hipLaunchKernelGGL(bias_fold1, dim3(1), blk, 0, stream, bq, U, tmpv);
    hipLaunchKernelGGL(bias_fold2, dim3(E_DIM / 256), blk, 0, stream, bq, U, tmpv, bqe);
    hipLaunchKernelGGL(bias_fold1, dim3(1), blk, 0, stream, bk, U, tmpv);
    hipLaunchKernelGGL(bias_fold2, dim3(E_DIM / 256), blk, 0, stream, bk, U, tmpv, bke);

    // 1. Weight folds: GT = W^T @ U  [E,R];  Wf = 0.4*U@GT^T + 0.6*W  [E,E]
    //    (condition(xW^T+b) == x@Wf^T + beff, since UU^T is symmetric)
    {
        dim3 gt(R_DIM / 128, E_DIM / 128, 1);
        dim3 gw(E_DIM / 128, E_DIM / 128, 1);
        hipLaunchKernelGGL((gemm_mfma<true>), gt, blk, 0, stream,
            WqTh, WqTl, Uth, Utl, nullptr, GTqh, GTql, nullptr, nullptr, nullptr,
            E_DIM, R_DIM, E_DIM, E_DIM, E_DIM, R_DIM, 1.0f, 0.0f);
        hipLaunchKernelGGL((gemm_mfma<true>), gw, blk, 0, stream,
            Uh, Ul, GTqh, GTql, nullptr, Wfqh, Wfql, Wqh, Wql, nullptr,
            E_DIM, E_DIM, R_DIM, R_DIM, R_DIM, E_DIM, 0.4f, 0.6f);
        hipLaunchKernelGGL((gemm_mfma<true>), gt, blk, 0, stream,
            WkTh, WkTl, Uth, Utl, nullptr, GTkh, GTkl, nullptr, nullptr, nullptr,
            E_DIM, R_DIM, E_DIM, E_DIM, E_DIM, R_DIM, 1.0f, 0.0f);
        hipLaunchKernelGGL((gemm_mfma<true>), gw, blk, 0, stream,
            Uh, Ul, GTkh, GTkl, nullptr, Wfkh, Wfkl, Wkh, Wkl, nullptr,
            E_DIM, E_DIM, R_DIM, R_DIM, R_DIM, E_DIM, 0.4f, 0.6f);
    }

    // 2. Projections: Qc = x@Wfq^T + bqe ; Kc = x@Wfk^T + bke ; V = x@Wv^T + bv
    {
        dim3 g(E_DIM / 128, M / 128, 1);
        hipLaunchKernelGGL((gemm_mfma<true>), g, blk, 0, stream,
            xh, xl, Wfqh, Wfql, nullptr, Qch, nullptr, nullptr, nullptr, bqe,
            M, E_DIM, E_DIM, E_DIM, E_DIM, E_DIM, 1.0f, 0.0f);
        hipLaunchKernelGGL((gemm_mfma<true>), g, blk, 0, stream,
            xh, xl, Wfkh, Wfkl, nullptr, Kch, nullptr, nullptr, nullptr, bke,
            M, E_DIM, E_DIM, E_DIM, E_DIM, E_DIM, 1.0f, 0.0f);
        hipLaunchKernelGGL((gemm_mfma<true>), g, blk, 0, stream,
            xh, xl, Wvh, Wvl, nullptr, Vh, nullptr, nullptr, nullptr, bv,
            M, E_DIM, E_DIM, E_DIM, E_DIM, E_DIM, 1.0f, 0.0f);
    }
    hipLaunchKernelGGL(transpose_v_bf16, dim3(L_SEQ / 32, D_HEAD / 32, B_SZ * H_N),
                       blk, 0, stream, Vh, Vth);

    // 3. Fused: scores -> softmax -> attn weights (fp32) + ctx (bf16 hi/lo)
    hipLaunchKernelGGL(attn_fused, dim3(L_SEQ / 64, B_SZ * H_N), blk, 0, stream,
                       Qch, Kch, Vth, attnF, ctxh, ctxl, mask, maskFlag);

    // 4. out = ctx @ Wo^T + bo  (split-bf16)
    {
        dim3 g(E_DIM / 128, M / 128, 1);
        hipLaunchKernelGGL((gemm_mfma<true>), g, blk, 0, stream,
            ctxh, ctxl, Woh, Wol, out, nullptr, nullptr, nullptr, nullptr, bo,
            M, E_DIM, E_DIM, E_DIM, E_DIM, E_DIM, 1.0f, 0.0f);
    }
}

// Round 6
// 1006.861 us; speedup vs baseline: 1.1429x; 1.1429x over previous
//
#include <hip/hip_runtime.h>
#include <cstddef>

// Problem constants (from reference):
#define L_SEQ  2048
#define B_SZ   2
#define E_DIM  1024
#define H_N    16
#define D_HEAD 64
#define R_DIM  256

typedef unsigned short u16;
using bf16x8 = __attribute__((ext_vector_type(8))) short;   // 8 bf16 (4 VGPRs)
using f32x4  = __attribute__((ext_vector_type(4))) float;   // MFMA accumulator

// RNE fp32 -> bf16 (matches v_cvt semantics)
__device__ __forceinline__ u16 bf16rne(float f) {
    unsigned u = __float_as_uint(f);
    return (u16)((u + 0x7FFFu + ((u >> 16) & 1u)) >> 16);
}
__device__ __forceinline__ float b2f(u16 h) {
    return __uint_as_float(((unsigned)h) << 16);
}

// Async global->LDS, 16B per lane: LDS dest = wave-uniform base + lane*16.
// Source is per-lane (pre-swizzled). Guide §5 / m97 / m173. HW-verified r4.
__device__ __forceinline__ void gload16(const u16* g, u16* l) {
    __builtin_amdgcn_global_load_lds(
        (const __attribute__((address_space(1))) void*)g,
        (__attribute__((address_space(3))) void*)l, 16, 0, 0);
}

// ---------------------------------------------------------------------------
// fp32 -> bf16 hi/lo conversion (grid-stride, float4 vectorized)
// ---------------------------------------------------------------------------
__global__ __launch_bounds__(256)
void convert_hilo(const float* __restrict__ in, u16* __restrict__ hi,
                  u16* __restrict__ lo, int n4)
{
    for (int i = blockIdx.x * 256 + threadIdx.x; i < n4; i += gridDim.x * 256) {
        float4 v = ((const float4*)in)[i];
        u16 h0 = bf16rne(v.x), h1 = bf16rne(v.y), h2 = bf16rne(v.z), h3 = bf16rne(v.w);
        uint2 hp;
        hp.x = (unsigned)h0 | ((unsigned)h1 << 16);
        hp.y = (unsigned)h2 | ((unsigned)h3 << 16);
        ((uint2*)hi)[i] = hp;
        u16 l0 = bf16rne(v.x - b2f(h0)), l1 = bf16rne(v.y - b2f(h1));
        u16 l2 = bf16rne(v.z - b2f(h2)), l3 = bf16rne(v.w - b2f(h3));
        uint2 lp;
        lp.x = (unsigned)l0 | ((unsigned)l1 << 16);
        lp.y = (unsigned)l2 | ((unsigned)l3 << 16);
        ((uint2*)lo)[i] = lp;
    }
}

// ---------------------------------------------------------------------------
// fp32 [rows][cols] -> bf16 hi/lo transposed [cols][rows]
// ---------------------------------------------------------------------------
__global__ __launch_bounds__(256)
void transpose_f32_hilo(const float* __restrict__ in, u16* __restrict__ oh,
                        u16* __restrict__ ol, int rows, int cols)
{
    __shared__ float t[32][33];
    const int tx = threadIdx.x & 31, ty = threadIdx.x >> 5;
    const int r0 = blockIdx.y * 32, c0 = blockIdx.x * 32;
    #pragma unroll
    for (int i = 0; i < 4; i++)
        t[ty + i * 8][tx] = in[(size_t)(r0 + ty + i * 8) * cols + c0 + tx];
    __syncthreads();
    #pragma unroll
    for (int i = 0; i < 4; i++) {
        float v = t[tx][ty + i * 8];
        u16 h = bf16rne(v);
        size_t o = (size_t)(c0 + ty + i * 8) * rows + r0 + tx;
        oh[o] = h;
        ol[o] = bf16rne(v - b2f(h));
    }
}

// ---------------------------------------------------------------------------
// V [L,B,E] bf16 -> Vt [B*H, D, L] bf16 (per-head transpose so PV is TRANSB)
// ---------------------------------------------------------------------------
__global__ __launch_bounds__(256)
void transpose_v_bf16(const u16* __restrict__ vh, u16* __restrict__ vt)
{
    __shared__ u16 t[32][34];
    const int tx = threadIdx.x & 31, ty = threadIdx.x >> 5;
    const int l0 = blockIdx.x * 32, d0 = blockIdx.y * 32;
    const int z = blockIdx.z, b = z >> 4, h = z & 15;
    #pragma unroll
    for (int i = 0; i < 4; i++)
        t[ty + i * 8][tx] =
            vh[(size_t)((l0 + ty + i * 8) * B_SZ + b) * E_DIM + h * D_HEAD + d0 + tx];
    __syncthreads();
    #pragma unroll
    for (int i = 0; i < 4; i++)
        vt[(size_t)(z * D_HEAD + d0 + ty + i * 8) * L_SEQ + l0 + tx] = t[tx][ty + i * 8];
}

// ---------------------------------------------------------------------------
// mask zero-detection + tiny helpers
// ---------------------------------------------------------------------------
__global__ void flag_init(int* f) { if (threadIdx.x == 0) *f = 0; }

__global__ __launch_bounds__(256)
void mask_scan(const float* __restrict__ m, int* __restrict__ f, int n4)
{
    int nz = 0;
    for (int i = blockIdx.x * 256 + threadIdx.x; i < n4; i += gridDim.x * 256) {
        float4 v = ((const float4*)m)[i];
        nz |= (v.x != 0.0f) | (v.y != 0.0f) | (v.z != 0.0f) | (v.w != 0.0f);
    }
    if (nz) atomicOr(f, 1);
}

__global__ __launch_bounds__(256)
void copy_f32(const float* __restrict__ s, float* __restrict__ d, int n)
{
    int i = blockIdx.x * 256 + threadIdx.x;
    if (i < n) d[i] = s[i];
}

// Bias fold: beff = 0.6*b + 0.4*U@(U^T@b)   (tiny, fp32)
__global__ __launch_bounds__(256)
void bias_fold1(const float* __restrict__ b, const float* __restrict__ U,
                float* __restrict__ tmp)
{
    const int r = threadIdx.x;
    float s = 0.0f;
    for (int e = 0; e < E_DIM; e++) s += U[(size_t)e * R_DIM + r] * b[e];
    tmp[r] = s;
}

__global__ __launch_bounds__(256)
void bias_fold2(const float* __restrict__ b, const float* __restrict__ U,
                const float* __restrict__ tmp, float* __restrict__ beff)
{
    const int e = blockIdx.x * 256 + threadIdx.x;
    float s = 0.0f;
    for (int r = 0; r < R_DIM; r++) s += U[(size_t)e * R_DIM + r] * tmp[r];
    beff[e] = 0.6f * b[e] + 0.4f * s;
}

// ---------------------------------------------------------------------------
// MFMA GEMM (z-batched, templated tile): C = alpha * A @ B^T + beta*Cin + bias
//   Per-operand offset = z * stride (parallel hi/lo arrays share strides).
//   Waves: 2x2; wave tile (BM/2)x(BN/2); frags FM=BM/32, FN=BN/32.
//   Staging: global_load_lds w=16 with pre-swizzled source (m173); LDS layout
//   [row][granule p] holds source granule p^(row&7) — identical to the
//   round-3/4 HW-verified layout; compute-side reads unchanged.
// ---------------------------------------------------------------------------
template <int BM, int BN, bool SPLIT>
__global__ __launch_bounds__(256)
void gemm_mfma(const u16* __restrict__ Ah, const u16* __restrict__ Al,
               const u16* __restrict__ Bh, const u16* __restrict__ Bl,
               float* __restrict__ Cf, u16* __restrict__ Ch, u16* __restrict__ Cl,
               const u16* __restrict__ Cinh, const u16* __restrict__ Cinl,
               const float* __restrict__ bias,
               int M, int N, int K, int lda, int ldb, int ldc,
               long aStr, long bStr, long cStr, long biasStr,
               float alpha, float beta)
{
    constexpr int BK = 64;
    constexpr int FM = BM / 32, FN = BN / 32;
    constexpr int ALO = BM * BK, BLO = BN * BK;
    __shared__ __align__(16) u16 As[(SPLIT ? 2 : 1) * BM * BK];
    __shared__ __align__(16) u16 Bs[(SPLIT ? 2 : 1) * BN * BK];

    const int tid = threadIdx.x;
    const int z = blockIdx.z;
    const long aOff = z * aStr, bOff = z * bStr, cOff = z * cStr;
    const long biasOff = z * biasStr;
    const int tm = blockIdx.y * BM, tn = blockIdx.x * BN;
    const int lane = tid & 63;
    const int fr = lane & 15, kg = lane >> 4;
    const int wave = tid >> 6;
    const int wm = (wave >> 1) * (BM / 2), wn = (wave & 1) * (BN / 2);

    const int sR8 = lane >> 3;                  // row within 8-row group
    const int sG  = ((lane & 7) ^ sR8) * 8;     // pre-swizzled source granule (u16)

    f32x4 acc[FM][FN] = {};

    for (int k0 = 0; k0 < K; k0 += BK) {
        #pragma unroll
        for (int c = 0; c < BM / 32; c++) {
            const int r0 = (c * 4 + wave) * 8;  // wave-uniform
            gload16(Ah + aOff + (size_t)(tm + r0 + sR8) * lda + k0 + sG, &As[r0 * BK]);
            if constexpr (SPLIT)
                gload16(Al + aOff + (size_t)(tm + r0 + sR8) * lda + k0 + sG, &As[ALO + r0 * BK]);
        }
        #pragma unroll
        for (int c = 0; c < BN / 32; c++) {
            const int r0 = (c * 4 + wave) * 8;
            gload16(Bh + bOff + (size_t)(tn + r0 + sR8) * ldb + k0 + sG, &Bs[r0 * BK]);
            if constexpr (SPLIT)
                gload16(Bl + bOff + (size_t)(tn + r0 + sR8) * ldb + k0 + sG, &Bs[BLO + r0 * BK]);
        }
        __syncthreads();   // drains vmcnt (compiler emits full waitcnt before barrier)

        #pragma unroll
        for (int ks = 0; ks < 2; ks++) {
            bf16x8 ah[FM], al[FM];
            #pragma unroll
            for (int m = 0; m < FM; m++) {
                int row = wm + m * 16 + fr;
                int p = (ks * 4 + kg) ^ (row & 7);
                ah[m] = *(const bf16x8*)&As[row * BK + p * 8];
                if constexpr (SPLIT)
                    al[m] = *(const bf16x8*)&As[ALO + row * BK + p * 8];
            }
            #pragma unroll
            for (int n = 0; n < FN; n++) {
                int col = wn + n * 16 + fr;
                int p = (ks * 4 + kg) ^ (col & 7);
                bf16x8 bh = *(const bf16x8*)&Bs[col * BK + p * 8];
                #pragma unroll
                for (int m = 0; m < FM; m++)
                    acc[m][n] = __builtin_amdgcn_mfma_f32_16x16x32_bf16(ah[m], bh, acc[m][n], 0, 0, 0);
                if constexpr (SPLIT) {
                    bf16x8 bl = *(const bf16x8*)&Bs[BLO + col * BK + p * 8];
                    #pragma unroll
                    for (int m = 0; m < FM; m++) {
                        acc[m][n] = __builtin_amdgcn_mfma_f32_16x16x32_bf16(al[m], bh, acc[m][n], 0, 0, 0);
                        acc[m][n] = __builtin_amdgcn_mfma_f32_16x16x32_bf16(ah[m], bl, acc[m][n], 0, 0, 0);
                    }
                }
            }
        }
        __syncthreads();
    }

    // epilogue: C/D layout col=lane&15, row=(lane>>4)*4+reg (m89-verified)
    #pragma unroll
    for (int m = 0; m < FM; m++) {
        int row0 = tm + wm + m * 16 + kg * 4;
        #pragma unroll
        for (int n = 0; n < FN; n++) {
            int col = tn + wn + n * 16 + fr;
            float bv = bias ? bias[biasOff + col] : 0.0f;
            #pragma unroll
            for (int j = 0; j < 4; j++) {
                size_t idx = cOff + (size_t)(row0 + j) * ldc + col;
                float v = alpha * acc[m][n][j] + bv;
                if (beta != 0.0f) {
                    float ci = b2f(Cinh[idx]);
                    if (Cinl) ci += b2f(Cinl[idx]);
                    v += beta * ci;
                }
                if (Cf) Cf[idx] = v;
                if (Ch) {
                    u16 h = bf16rne(v);
                    Ch[idx] = h;
                    if (Cl) Cl[idx] = bf16rne(v - b2f(h));
                }
            }
        }
    }
}

// ---------------------------------------------------------------------------
// Fused attention (HW-verified round 3/4): scores (QK^T/8 + mask) ->
// exact 2-pass softmax -> attn weights (fp32) + PV context (bf16 hi/lo).
// 64 q-rows per block, 4 waves x 16 q-rows. Byte-identical to round 4.
// ---------------------------------------------------------------------------
__global__ __launch_bounds__(256)
void attn_fused(const u16* __restrict__ Qc, const u16* __restrict__ Kc,
                const u16* __restrict__ Vt, float* __restrict__ attn,
                u16* __restrict__ ctxh, u16* __restrict__ ctxl,
                const float* __restrict__ mask, const int* __restrict__ maskFlag)
{
    __shared__ __align__(16) u16 Qs[64 * 64];   // [q][k]  swizzled, 8 KB
    __shared__ __align__(16) u16 Ks[64 * 64];   // [kv][k] swizzled, 8 KB
    __shared__ __align__(16) u16 Vs[64 * 64];   // [d][kv] swizzled, 8 KB
    __shared__ __align__(16) u16 Ps[4][16 * 64];// per-wave [q][kv] swizzled, 8 KB

    const int tid = threadIdx.x;
    const int z  = blockIdx.y;                 // b*16 + h
    const int q0 = blockIdx.x * 64;
    const int qkOff = (z >> 4) * E_DIM + (z & 15) * D_HEAD;
    const long vtOff = (long)z * D_HEAD * L_SEQ;
    const long aOff  = (long)z * L_SEQ * L_SEQ;
    const int ldq = B_SZ * E_DIM;              // 2048

    const int lane = tid & 63;
    const int fr = lane & 15, kg = lane >> 4;
    const int wave = tid >> 6;
    const int wq = wave * 16;

    const bool useMask = maskFlag[0] != 0;
    const int sR8 = lane >> 3;
    const int sG  = ((lane & 7) ^ sR8) * 8;    // pre-swizzled source granule

    // ---- stage Q tile [64][64] via global_load_lds ----
    #pragma unroll
    for (int c = 0; c < 2; c++) {
        const int r0 = (c * 4 + wave) * 8;
        gload16(Qc + (size_t)(q0 + r0 + sR8) * ldq + qkOff + sG, &Qs[r0 * 64]);
    }
    __syncthreads();
    bf16x8 qf[2];
    #pragma unroll
    for (int ks = 0; ks < 2; ks++) {
        int row = wq + fr;
        qf[ks] = *(const bf16x8*)&Qs[row * 64 + ((ks * 4 + kg) ^ (row & 7)) * 8];
    }
    __syncthreads();   // Qs dead

    float mrow[4], lrow[4];
    #pragma unroll
    for (int j = 0; j < 4; j++) { mrow[j] = -3.4e38f; lrow[j] = 0.0f; }

    // ================= pass 1: row max & sum =================
    for (int kt = 0; kt < L_SEQ / 64; kt++) {
        const int kv0 = kt * 64;
        #pragma unroll
        for (int c = 0; c < 2; c++) {
            const int r0 = (c * 4 + wave) * 8;
            gload16(Kc + (size_t)(kv0 + r0 + sR8) * ldq + qkOff + sG, &Ks[r0 * 64]);
        }
        __syncthreads();

        f32x4 acc[4] = {};
        #pragma unroll
        for (int ks = 0; ks < 2; ks++) {
            #pragma unroll
            for (int n = 0; n < 4; n++) {
                int col = n * 16 + fr;
                bf16x8 bh = *(const bf16x8*)&Ks[col * 64 + ((ks * 4 + kg) ^ (col & 7)) * 8];
                acc[n] = __builtin_amdgcn_mfma_f32_16x16x32_bf16(qf[ks], bh, acc[n], 0, 0, 0);
            }
        }
        __syncthreads();   // Ks consumed before restage

        #pragma unroll
        for (int j = 0; j < 4; j++) {
            float v[4];
            #pragma unroll
            for (int n = 0; n < 4; n++) {
                v[n] = acc[n][j] * 0.125f;
                if (useMask)
                    v[n] += mask[(size_t)(q0 + wq + kg * 4 + j) * L_SEQ + kv0 + n * 16 + fr];
            }
            float t0 = fmaxf(fmaxf(v[0], v[1]), fmaxf(v[2], v[3]));
            float nm = fmaxf(mrow[j], t0);
            float sc = __expf(mrow[j] - nm);
            float s  = __expf(v[0] - nm) + __expf(v[1] - nm)
                     + __expf(v[2] - nm) + __expf(v[3] - nm);
            lrow[j] = lrow[j] * sc + s;
            mrow[j] = nm;
        }
    }

    // merge (m,l) across the 16-lane fr-group
    #pragma unroll
    for (int j = 0; j < 4; j++) {
        float m_ = mrow[j], l_ = lrow[j];
        #pragma unroll
        for (int off = 1; off < 16; off <<= 1) {
            float mo = __shfl_xor(m_, off, 64);
            float lo2 = __shfl_xor(l_, off, 64);
            float M = fmaxf(m_, mo);
            l_ = l_ * __expf(m_ - M) + lo2 * __expf(mo - M);
            m_ = M;
        }
        mrow[j] = m_;
        lrow[j] = 1.0f / l_;
    }

    // ================= pass 2: normalized attn write + PV =================
    u16* Pw = &Ps[wave][0];
    f32x4 acc_o[4] = {};

    for (int kt = 0; kt < L_SEQ / 64; kt++) {
        const int kv0 = kt * 64;
        #pragma unroll
        for (int c = 0; c < 2; c++) {
            const int r0 = (c * 4 + wave) * 8;
            gload16(Kc + (size_t)(kv0 + r0 + sR8) * ldq + qkOff + sG, &Ks[r0 * 64]);
            gload16(Vt + vtOff + (size_t)(r0 + sR8) * L_SEQ + kv0 + sG, &Vs[r0 * 64]);
        }
        __syncthreads();

        f32x4 acc[4] = {};
        #pragma unroll
        for (int ks = 0; ks < 2; ks++) {
            #pragma unroll
            for (int n = 0; n < 4; n++) {
                int col = n * 16 + fr;
                bf16x8 bh = *(const bf16x8*)&Ks[col * 64 + ((ks * 4 + kg) ^ (col & 7)) * 8];
                acc[n] = __builtin_amdgcn_mfma_f32_16x16x32_bf16(qf[ks], bh, acc[n], 0, 0, 0);
            }
        }

        // P = exp(s - m) / l : write fp32 attn + bf16 into wave-private LDS
        #pragma unroll
        for (int n = 0; n < 4; n++) {
            #pragma unroll
            for (int j = 0; j < 4; j++) {
                int row = kg * 4 + j;
                int col = n * 16 + fr;
                float v = acc[n][j] * 0.125f;
                if (useMask)
                    v += mask[(size_t)(q0 + wq + row) * L_SEQ + kv0 + col];
                float p = __expf(v - mrow[j]) * lrow[j];
                attn[aOff + (size_t)(q0 + wq + row) * L_SEQ + kv0 + col] = p;
                Pw[row * 64 + ((col >> 3) ^ (row & 7)) * 8 + (col & 7)] = bf16rne(p);
            }
        }

        // pin order: Pw writes precede same-wave Pw reads (rule #18 class)
        asm volatile("" ::: "memory");

        // PV: O[16 q][64 d] += P[16 q][64 kv] @ Vt[64 d][64 kv]^T
        #pragma unroll
        for (int ks = 0; ks < 2; ks++) {
            int rowA = fr;
            bf16x8 pa = *(const bf16x8*)&Pw[rowA * 64 + ((ks * 4 + kg) ^ (rowA & 7)) * 8];
            #pragma unroll
            for (int n = 0; n < 4; n++) {
                int d = n * 16 + fr;
                bf16x8 vb = *(const bf16x8*)&Vs[d * 64 + ((ks * 4 + kg) ^ (d & 7)) * 8];
                acc_o[n] = __builtin_amdgcn_mfma_f32_16x16x32_bf16(pa, vb, acc_o[n], 0, 0, 0);
            }
        }
        __syncthreads();   // Ks/Vs consumed before restage
    }

    // ---- epilogue: ctx bf16 hi/lo, head-sliced [L,B,E] ----
    #pragma unroll
    for (int n = 0; n < 4; n++) {
        #pragma unroll
        for (int j = 0; j < 4; j++) {
            int row = q0 + wq + kg * 4 + j;
            int d = n * 16 + fr;
            float v = acc_o[n][j];
            size_t idx = (size_t)row * ldq + qkOff + d;
            u16 h = bf16rne(v);
            ctxh[idx] = h;
            ctxl[idx] = bf16rne(v - b2f(h));
        }
    }
}

// ---------------------------------------------------------------------------
extern "C" void kernel_launch(void* const* d_in, const int* in_sizes, int n_in,
                              void* d_out, int out_size, void* d_ws, size_t ws_size,
                              hipStream_t stream)
{
    const float* x    = (const float*)d_in[0];
    const float* mask = (const float*)d_in[1];
    const float* Wq   = (const float*)d_in[2];
    const float* bq   = (const float*)d_in[3];
    const float* Wk   = (const float*)d_in[4];
    const float* bk   = (const float*)d_in[5];
    const float* Wv   = (const float*)d_in[6];
    const float* bv   = (const float*)d_in[7];
    const float* Wo   = (const float*)d_in[8];
    const float* bo   = (const float*)d_in[9];
    const float* U    = (const float*)d_in[10];

    float* out   = (float*)d_out;                               // [L,B,E]
    float* attnF = out + (size_t)L_SEQ * B_SZ * E_DIM;          // [B,H,L,L]

    const int SZ  = L_SEQ * B_SZ * E_DIM;   // 4,194,304
    const int WSZ = E_DIM * E_DIM;          // 1,048,576
    const int USZ = E_DIM * R_DIM;          //   262,144

    // ---- persistent ws: EXACTLY 6*SZ + 2*WSZ u16 = 54,525,952 B, which is
    // the proven ws_size lower bound (round-0 layout). Nothing may exceed it.
    u16* Qch  = (u16*)d_ws;
    u16* Kch  = Qch + SZ;
    u16* Vh   = Kch + SZ;
    u16* Vth  = Vh + SZ;           // V^T per head: [B*H, D, L]
    u16* ctxh = Vth + SZ;
    u16* ctxl = ctxh + SZ;
    u16* Woh  = ctxl + SZ;
    u16* Wol  = Woh + WSZ;
    // maskFlag lives in the OUT region of d_out: out[] is dead until the final
    // out-projection GEMM (which runs after attn_fused has consumed the flag).
    int* maskFlag = (int*)(out + (size_t)SZ) - 1;

    // ---- pre-attn scratch in the (not-yet-written) attn region (~48 MB) ----
    u16* sc   = (u16*)attnF;
    u16* xh   = sc;          u16* xl   = xh + SZ;
    u16* Wqh  = xl + SZ;     u16* Wql  = Wqh + WSZ;   // Wq/Wk hi/lo (Cin for fold)
    u16* Wkh  = Wql + WSZ;   u16* Wkl  = Wkh + WSZ;
    // folded/projection weights, stride 2*WSZ between z-slots {q,k,v}:
    u16* Wfqh = Wkl + WSZ;   u16* Wfql = Wfqh + WSZ;
    u16* Wfkh = Wfql + WSZ;  u16* Wfkl = Wfkh + WSZ;
    u16* Wvh  = Wfkl + WSZ;  u16* Wvl  = Wvh + WSZ;   // convert_hilo writes here
    u16* Uh   = Wvl + WSZ;   u16* Ul   = Uh + USZ;
    u16* Uth  = Ul + USZ;    u16* Utl  = Uth + USZ;   // U^T [R,E]
    u16* WqTh = Utl + USZ;   u16* WqTl = WqTh + WSZ;  // W^T [E,E], stride 2*WSZ
    u16* WkTh = WqTl + WSZ;  u16* WkTl = WkTh + WSZ;
    u16* GTqh = WkTl + WSZ;  u16* GTql = GTqh + USZ;  // W^T@U [E,R], stride 2*USZ
    u16* GTkh = GTql + USZ;  u16* GTkl = GTkh + USZ;
    float* bqkv = (float*)(GTkl + USZ);               // folded biases [3][E]
    float* tmpv = bqkv + 3 * E_DIM;

    const dim3 blk(256);
    const int M = L_SEQ * B_SZ;  // 4096

    // 0a. mask zero-detection flag (stored in out region; consumed by attn)
    hipLaunchKernelGGL(flag_init, dim3(1), dim3(64), 0, stream, maskFlag);
    hipLaunchKernelGGL(mask_scan, dim3(512), blk, 0, stream,
                       mask, maskFlag, (L_SEQ * L_SEQ) / 4);

    // 0b. fp32 -> bf16 hi/lo conversions + transposes
    hipLaunchKernelGGL(convert_hilo, dim3(2048), blk, 0, stream, x,  xh,  xl,  SZ / 4);
    hipLaunchKernelGGL(convert_hilo, dim3(512),  blk, 0, stream, Wq, Wqh, Wql, WSZ / 4);
    hipLaunchKernelGGL(convert_hilo, dim3(512),  blk, 0, stream, Wk, Wkh, Wkl, WSZ / 4);
    hipLaunchKernelGGL(convert_hilo, dim3(512),  blk, 0, stream, Wv, Wvh, Wvl, WSZ / 4);
    hipLaunchKernelGGL(convert_hilo, dim3(512),  blk, 0, stream, Wo, Woh, Wol, WSZ / 4);
    hipLaunchKernelGGL(convert_hilo, dim3(128),  blk, 0, stream, U,  Uh,  Ul,  USZ / 4);
    hipLaunchKernelGGL(transpose_f32_hilo, dim3(R_DIM / 32, E_DIM / 32), blk, 0, stream,
                       U, Uth, Utl, E_DIM, R_DIM);
    hipLaunchKernelGGL(transpose_f32_hilo, dim3(E_DIM / 32, E_DIM / 32), blk, 0, stream,
                       Wq, WqTh, WqTl, E_DIM, E_DIM);
    hipLaunchKernelGGL(transpose_f32_hilo, dim3(E_DIM / 32, E_DIM / 32), blk, 0, stream,
                       Wk, WkTh, WkTl, E_DIM, E_DIM);

    // 0c. bias folds: beff = 0.6*b + 0.4*U@(U^T@b);  bv copied to slot 2
    hipLaunchKernelGGL(bias_fold1, dim3(1), blk, 0, stream, bq, U, tmpv);
    hipLaunchKernelGGL(bias_fold2, dim3(E_DIM / 256), blk, 0, stream, bq, U, tmpv, bqkv);
    hipLaunchKernelGGL(bias_fold1, dim3(1), blk, 0, stream, bk, U, tmpv);
    hipLaunchKernelGGL(bias_fold2, dim3(E_DIM / 256), blk, 0, stream, bk, U, tmpv, bqkv + E_DIM);
    hipLaunchKernelGGL(copy_f32, dim3(E_DIM / 256), blk, 0, stream, bv, bqkv + 2 * E_DIM, E_DIM);

    // 1. Weight folds, z-batched over {q,k} at 64x64 tiles (128 / 512 blocks):
    //    GT = W^T @ U  [E,R];  Wf = 0.4*U@GT^T + 0.6*W
    hipLaunchKernelGGL((gemm_mfma<64, 64, true>), dim3(R_DIM / 64, E_DIM / 64, 2), blk, 0, stream,
        WqTh, WqTl, Uth, Utl, nullptr, GTqh, GTqh + USZ, nullptr, nullptr, nullptr,
        E_DIM, R_DIM, E_DIM, E_DIM, E_DIM, R_DIM,
        (long)2 * WSZ, 0L, (long)2 * USZ, 0L, 1.0f, 0.0f);
    hipLaunchKernelGGL((gemm_mfma<64, 64, true>), dim3(E_DIM / 64, E_DIM / 64, 2), blk, 0, stream,
        Uh, Ul, GTqh, GTqh + USZ, nullptr, Wfqh, Wfqh + WSZ, Wqh, Wqh + WSZ, nullptr,
        E_DIM, E_DIM, R_DIM, R_DIM, R_DIM, E_DIM,
        0L, (long)2 * USZ, (long)2 * WSZ, 0L, 0.4f, 0.6f);

    // 2. Projections, z-batched over {Q,K,V} at 128x64 tiles (1536 blocks,
    //    48 KB LDS -> 3 blocks/CU): C = x @ Wf^T + beff  -> Qch | Kch | Vh
    hipLaunchKernelGGL((gemm_mfma<128, 64, true>), dim3(E_DIM / 64, M / 128, 3), blk, 0, stream,
        xh, xl, Wfqh, Wfqh + WSZ, nullptr, Qch, nullptr, nullptr, nullptr, bqkv,
        M, E_DIM, E_DIM, E_DIM, E_DIM, E_DIM,
        0L, (long)2 * WSZ, (long)SZ, (long)E_DIM, 1.0f, 0.0f);

    hipLaunchKernelGGL(transpose_v_bf16, dim3(L_SEQ / 32, D_HEAD / 32, B_SZ * H_N),
                       blk, 0, stream, Vh, Vth);

    // 3. Fused: scores -> softmax -> attn weights (fp32) + ctx (bf16 hi/lo)
    hipLaunchKernelGGL(attn_fused, dim3(L_SEQ / 64, B_SZ * H_N), blk, 0, stream,
                       Qch, Kch, Vth, attnF, ctxh, ctxl, mask, maskFlag);

    // 4. out = ctx @ Wo^T + bo  (split-bf16, 128x64 tile, 512 blocks)
    //    (overwrites the out region, including the spent maskFlag bytes)
    hipLaunchKernelGGL((gemm_mfma<128, 64, true>), dim3(E_DIM / 64, M / 128, 1), blk, 0, stream,
        ctxh, ctxl, Woh, Wol, out, nullptr, nullptr, nullptr, nullptr, bo,
        M, E_DIM, E_DIM, E_DIM, E_DIM, E_DIM,
        0L, 0L, 0L, 0L, 1.0f, 0.0f);
}